// Round 1
// 843.599 us; speedup vs baseline: 1.0248x; 1.0248x over previous
//
#include <hip/hip_runtime.h>
#include <hip/hip_bf16.h>
#include <cstdint>
#include <cstddef>

typedef __hip_bfloat16 bf16_t;
typedef __attribute__((ext_vector_type(8))) __bf16 bf16x8;
typedef __attribute__((ext_vector_type(4))) float f32x4;

__device__ __forceinline__ void gld_lds16(const void* g, void* l) {
    __builtin_amdgcn_global_load_lds(
        (const __attribute__((address_space(1))) void*)(g),
        (__attribute__((address_space(3))) void*)(l), 16, 0, 0);
}

// ---------------- cast fp32 -> bf16 (n % 4 == 0) ----------------
__global__ void k_cast(const float* __restrict__ in, bf16_t* __restrict__ out, long n) {
    long i = ((long)blockIdx.x * blockDim.x + threadIdx.x) * 4;
    if (i >= n) return;
    float4 v = *(const float4*)(in + i);
    out[i + 0] = __float2bfloat16(v.x);
    out[i + 1] = __float2bfloat16(v.y);
    out[i + 2] = __float2bfloat16(v.z);
    out[i + 3] = __float2bfloat16(v.w);
}

// cast with zero row padding: rows [rows_in, rows_out) -> 0
__global__ void k_cast_pad(const float* __restrict__ in, bf16_t* __restrict__ out,
                           int rows_in, int rows_out, int cols) {
    long i = ((long)blockIdx.x * blockDim.x + threadIdx.x) * 4;
    long n = (long)rows_out * cols;
    if (i >= n) return;
    int r = (int)(i / cols);
    if (r < rows_in) {
        float4 v = *(const float4*)(in + i);
        out[i + 0] = __float2bfloat16(v.x);
        out[i + 1] = __float2bfloat16(v.y);
        out[i + 2] = __float2bfloat16(v.z);
        out[i + 3] = __float2bfloat16(v.w);
    } else {
        bf16_t z = __float2bfloat16(0.f);
        out[i + 0] = z; out[i + 1] = z; out[i + 2] = z; out[i + 3] = z;
    }
}

// ---------------- transpose + cast: in [R,C] fp32 -> out [C,R] bf16 ----------------
__global__ void k_transpose_cast(const float* __restrict__ in, bf16_t* __restrict__ out,
                                 int R, int C) {
    __shared__ float tile[32][33];
    int bx = blockIdx.x * 32;
    int by = blockIdx.y * 32;
    int tx = threadIdx.x & 31, ty = threadIdx.x >> 5;
    #pragma unroll
    for (int j = 0; j < 32; j += 8)
        tile[ty + j][tx] = in[(size_t)(by + ty + j) * C + bx + tx];
    __syncthreads();
    #pragma unroll
    for (int j = 0; j < 32; j += 8)
        out[(size_t)(bx + ty + j) * R + by + tx] = __float2bfloat16(tile[tx][ty + j]);
}

// ---------------- adapter: v_ip[b][n] = sum_k ae[b][k] * Wva[k][n] ----------------
__global__ void k_adapter(const float* __restrict__ ae, const float* __restrict__ Wva,
                          float* __restrict__ vip) {
    int g = blockIdx.x * 256 + threadIdx.x;
    int b = g / 1280, n = g % 1280;
    const float* a = ae + b * 768;
    float acc = 0.f;
    for (int k = 0; k < 768; ++k) acc += a[k] * Wva[(size_t)k * 1280 + n];
    vip[g] = acc;
}

// ---------------- bf16 GEMM: C[M,N] = A[M,K] @ Bt[N,K]^T (+bias) ----------------
// 128x128 tile, BK=32, 4 waves each 64x64. m97 structure. Kept for the small
// K/V projection GEMMs (M=640 doesn't fit the 256-tile kernel cleanly).
template <bool OUT_BF16, bool ADD_BIAS, bool SWZ>
__global__ __launch_bounds__(256, 2) void k_gemm_bt(
    const bf16_t* __restrict__ A, const bf16_t* __restrict__ Bt,
    void* __restrict__ Cv, const float* __restrict__ bias, int M, int N, int K,
    int snt, int mtx) {
    __shared__ __align__(16) bf16_t As[128 * 32];
    __shared__ __align__(16) bf16_t Bs[128 * 32];
    const int tid = threadIdx.x;
    int m0, n0;
    if constexpr (SWZ) {
        int id = blockIdx.x;
        int xcd = id & 7, j = id >> 3;
        m0 = (xcd * mtx + j / snt) * 128;
        n0 = (j % snt) * 128;
    } else {
        m0 = blockIdx.y * 128;
        n0 = blockIdx.x * 128;
    }
    const int wave = tid >> 6, lane = tid & 63;
    const int wm = (wave >> 1) * 64, wn = (wave & 1) * 64;
    const int quad = lane >> 4, l16 = lane & 15;

    f32x4 acc[4][4] = {};

    const int c0 = tid, c1 = tid + 256;
    const int r0 = c0 >> 2, o0 = (c0 & 3) * 8;
    const int r1 = c1 >> 2, o1 = (c1 & 3) * 8;
    const bf16_t* a0 = A + (size_t)(m0 + r0) * K + o0;
    const bf16_t* a1 = A + (size_t)(m0 + r1) * K + o1;
    const bf16_t* b0 = Bt + (size_t)(n0 + r0) * K + o0;
    const bf16_t* b1 = Bt + (size_t)(n0 + r1) * K + o1;

    for (int k0 = 0; k0 < K; k0 += 32) {
        __syncthreads();
        gld_lds16(a0 + k0, As + c0 * 8);
        gld_lds16(a1 + k0, As + c1 * 8);
        gld_lds16(b0 + k0, Bs + c0 * 8);
        gld_lds16(b1 + k0, Bs + c1 * 8);
        __syncthreads();
        bf16x8 af[4], bfv[4];
        #pragma unroll
        for (int t = 0; t < 4; ++t) {
            af[t]  = *(const bf16x8*)(As + (wm + t * 16 + l16) * 32 + quad * 8);
            bfv[t] = *(const bf16x8*)(Bs + (wn + t * 16 + l16) * 32 + quad * 8);
        }
        #pragma unroll
        for (int mt = 0; mt < 4; ++mt)
            #pragma unroll
            for (int nt = 0; nt < 4; ++nt)
                acc[mt][nt] = __builtin_amdgcn_mfma_f32_16x16x32_bf16(af[mt], bfv[nt], acc[mt][nt], 0, 0, 0);
    }

    if constexpr (OUT_BF16) {
        bf16_t* C = (bf16_t*)Cv;
        #pragma unroll
        for (int mt = 0; mt < 4; ++mt)
            #pragma unroll
            for (int rg = 0; rg < 4; ++rg) {
                int row = m0 + wm + mt * 16 + quad * 4 + rg;
                #pragma unroll
                for (int nt = 0; nt < 4; ++nt) {
                    int col = n0 + wn + nt * 16 + l16;
                    C[(size_t)row * N + col] = __float2bfloat16(acc[mt][nt][rg]);
                }
            }
    } else {
        float* C = (float*)Cv;
        float bv[4];
        #pragma unroll
        for (int nt = 0; nt < 4; ++nt)
            bv[nt] = ADD_BIAS ? bias[n0 + wn + nt * 16 + l16] : 0.f;
        #pragma unroll
        for (int mt = 0; mt < 4; ++mt)
            #pragma unroll
            for (int rg = 0; rg < 4; ++rg) {
                int row = m0 + wm + mt * 16 + quad * 4 + rg;
                #pragma unroll
                for (int nt = 0; nt < 4; ++nt) {
                    int col = n0 + wn + nt * 16 + l16;
                    C[(size_t)row * N + col] = acc[mt][nt][rg] + bv[nt];
                }
            }
    }
}

// ---------------- bf16 GEMM, 256x256 tile, BK=64, 8-phase pipeline ----------------
// 512 threads = 8 waves (2M x 4N), per-wave output 128x64. LDS 128 KiB:
// 2 K-tile double buffer x (A 256x64 + B 256x64) bf16. Per phase: ds_read one
// register subtile + stage one half-tile (2x global_load_lds w16) -> s_barrier
// -> lgkmcnt(0) -> setprio(1) 16 MFMA setprio(0) -> s_barrier. vmcnt(6) once
// per K-tile (3 half-tiles in flight across barriers; never drained to 0 in
// the main loop).
//
// Half-tiles per K-tile, in CONSUMPTION order (each is 16 KB, contiguous in LDS):
//   H1 = A rows used by quad mh=0  (physical A rows [0,128)   = logical {0-63,128-191})
//   H2 = B rows used by quad nh=0  (physical B rows [0,128))
//   H3 = B rows used by quad nh=1  (physical B rows [128,256))
//   H4 = A rows used by quad mh=1  (physical A rows [128,256))
// Phase p1 computes (mh0,nh0) reading H1,H2; p2 (mh0,nh1) reads H3; p3 (mh1,nh0)
// reads H4; p4 (mh1,nh1) reuses registers. Stages: p1 -> H4(t+1) [other buffer],
// p2 -> H1(t+2), p3 -> H2(t+2), p4 -> H3(t+2) [same buffer, each region dead
// since >= 1 closing barrier earlier]. vmcnt(6) at p4 completes H4(t+1) and all
// older -> tile t+1 fully resident before its first read.
//
// Bank-conflict swizzle (T2): physical col = logical col ^ ((physical_row&7)*8)
// elements. global_load_lds writes LDS linearly, so the swizzle is realized by
// permuting the per-lane GLOBAL source column (rule #21); ds_read applies the
// same XOR. 16 lanes reading 16 consecutive rows then hit 8 distinct 16B slots
// (2 lanes/bank = free) instead of a single bank column.
template <bool OUT_BF16, bool ADD_BIAS>
__global__ __launch_bounds__(512, 2) void k_gemm256(
    const bf16_t* __restrict__ A, const bf16_t* __restrict__ Bt,
    void* __restrict__ Cv, const float* __restrict__ bias,
    int M, int N, int K, int snt, int mtx) {
    (void)M;
    __shared__ __align__(16) bf16_t As[2][256 * 64];
    __shared__ __align__(16) bf16_t Bs[2][256 * 64];
    const int tid = threadIdx.x;
    const int id = blockIdx.x;
    const int xcd = id & 7, jb = id >> 3;
    const int m0 = (xcd * mtx + jb / snt) * 256;
    const int n0 = (jb % snt) * 256;
    const int wave = tid >> 6, lane = tid & 63;
    const int wm = wave >> 2, wn = wave & 3;
    const int quad = lane >> 4, l16 = lane & 15;

    // ---- staging geometry (per thread, j in {0,1} chunks of each half-tile)
    const int lr0 = tid >> 3;                               // LDS row for j=0 (0..63)
    const int cst = ((tid & 7) * 8) ^ ((lr0 & 7) * 8);      // swizzled source col (same for j=1)
    const bf16_t* pA0 = A + (size_t)(m0 + lr0) * K + cst;   // + MH*64*K ; j=1: +128*K
    const bf16_t* pA1 = pA0 + (size_t)128 * K;
    const bf16_t* pB0 = Bt + (size_t)(n0 + ((lr0 >> 5) << 6) + (lr0 & 31)) * K + cst; // + NH*32*K
    const bf16_t* pB1 = pB0 + (size_t)128 * K;
    const int eA0 = tid * 8, eA1 = 4096 + tid * 8;          // LDS element offsets (linear dest)

    // ---- fragment read geometry
    const int xorc = (l16 & 7) * 8;
    const int c0x = (quad * 8) ^ xorc;                      // ks=0 swizzled col
    const int c1x = (32 + quad * 8) ^ xorc;                 // ks=1 swizzled col
    const int arow = (wm * 64 + l16) * 64;                  // + MH*8192 + mt*1024
    const int brow = (wn * 32 + l16) * 64;                  // + NH*8192 + nt*1024

    f32x4 acc[8][4] = {};
    bf16x8 af[4][2], bfr[4][2];

#define STAGE_A_(WB, MH, KT) do { \
    size_t ko_ = (size_t)(KT) * 64 + (size_t)(MH) * 64 * K; \
    gld_lds16(pA0 + ko_, &As[WB][(MH) * 8192 + eA0]); \
    gld_lds16(pA1 + ko_, &As[WB][(MH) * 8192 + eA1]); } while (0)
#define STAGE_B_(WB, NH, KT) do { \
    size_t ko_ = (size_t)(KT) * 64 + (size_t)(NH) * 32 * K; \
    gld_lds16(pB0 + ko_, &Bs[WB][(NH) * 8192 + eA0]); \
    gld_lds16(pB1 + ko_, &Bs[WB][(NH) * 8192 + eA1]); } while (0)
#define LOAD_A_(RB, MH) do { _Pragma("unroll") \
    for (int mt = 0; mt < 4; ++mt) { \
      const bf16_t* p_ = &As[RB][(MH) * 8192 + arow + mt * 1024]; \
      af[mt][0] = *(const bf16x8*)(p_ + c0x); \
      af[mt][1] = *(const bf16x8*)(p_ + c1x); } } while (0)
#define LOAD_B_(RB, NH) do { _Pragma("unroll") \
    for (int nt = 0; nt < 2; ++nt) { \
      const bf16_t* p_ = &Bs[RB][(NH) * 8192 + brow + nt * 1024]; \
      bfr[(NH) * 2 + nt][0] = *(const bf16x8*)(p_ + c0x); \
      bfr[(NH) * 2 + nt][1] = *(const bf16x8*)(p_ + c1x); } } while (0)
#define MMA_(MH, NH) do { _Pragma("unroll") \
    for (int mt = 0; mt < 4; ++mt) _Pragma("unroll") \
    for (int nt = 0; nt < 2; ++nt) _Pragma("unroll") \
    for (int ks = 0; ks < 2; ++ks) \
      acc[(MH) * 4 + mt][(NH) * 2 + nt] = __builtin_amdgcn_mfma_f32_16x16x32_bf16( \
          af[mt][ks], bfr[(NH) * 2 + nt][ks], acc[(MH) * 4 + mt][(NH) * 2 + nt], 0, 0, 0); } while (0)
#define BARRIER_ asm volatile("s_barrier" ::: "memory")
#define WAITL0_ do { asm volatile("s_waitcnt lgkmcnt(0)" ::: "memory"); \
    __builtin_amdgcn_sched_barrier(0); } while (0)

#define TILEFULL(T, RB) do { \
    LOAD_A_(RB, 0); LOAD_B_(RB, 0); \
    STAGE_A_((RB) ^ 1, 1, (T) + 1); \
    asm volatile("s_waitcnt lgkmcnt(8)" ::: "memory"); \
    BARRIER_; WAITL0_; \
    __builtin_amdgcn_s_setprio(1); MMA_(0, 0); __builtin_amdgcn_s_setprio(0); \
    BARRIER_; \
    LOAD_B_(RB, 1); \
    STAGE_A_(RB, 0, (T) + 2); \
    BARRIER_; WAITL0_; \
    __builtin_amdgcn_s_setprio(1); MMA_(0, 1); __builtin_amdgcn_s_setprio(0); \
    BARRIER_; \
    LOAD_A_(RB, 1); \
    STAGE_B_(RB, 0, (T) + 2); \
    BARRIER_; WAITL0_; \
    __builtin_amdgcn_s_setprio(1); MMA_(1, 0); __builtin_amdgcn_s_setprio(0); \
    BARRIER_; \
    STAGE_B_(RB, 1, (T) + 2); \
    asm volatile("s_waitcnt vmcnt(6)" ::: "memory"); \
    BARRIER_; \
    __builtin_amdgcn_s_setprio(1); MMA_(1, 1); __builtin_amdgcn_s_setprio(0); \
    BARRIER_; \
  } while (0)

#define TILEEPI(T, RB) do { \
    LOAD_A_(RB, 0); LOAD_B_(RB, 0); \
    STAGE_A_((RB) ^ 1, 1, (T) + 1); \
    asm volatile("s_waitcnt lgkmcnt(8)" ::: "memory"); \
    BARRIER_; WAITL0_; \
    __builtin_amdgcn_s_setprio(1); MMA_(0, 0); __builtin_amdgcn_s_setprio(0); \
    BARRIER_; \
    LOAD_B_(RB, 1); \
    BARRIER_; WAITL0_; \
    __builtin_amdgcn_s_setprio(1); MMA_(0, 1); __builtin_amdgcn_s_setprio(0); \
    BARRIER_; \
    LOAD_A_(RB, 1); \
    BARRIER_; WAITL0_; \
    __builtin_amdgcn_s_setprio(1); MMA_(1, 0); __builtin_amdgcn_s_setprio(0); \
    BARRIER_; \
    asm volatile("s_waitcnt vmcnt(0)" ::: "memory"); \
    BARRIER_; \
    __builtin_amdgcn_s_setprio(1); MMA_(1, 1); __builtin_amdgcn_s_setprio(0); \
    BARRIER_; \
  } while (0)

#define TILELAST(RB) do { \
    LOAD_A_(RB, 0); LOAD_B_(RB, 0); \
    MMA_(0, 0); \
    LOAD_B_(RB, 1); \
    MMA_(0, 1); \
    LOAD_A_(RB, 1); \
    MMA_(1, 0); \
    MMA_(1, 1); \
  } while (0)

    const int NT = K >> 6;  // requires K % 128 == 0 (NT even, NT >= 4)

    // prologue: tile0 H1..H4, tile1 H1..H3 (7 half-tiles, 14 loads);
    // vmcnt(6) -> tile0 resident, tile1 H1-3 in flight.
    STAGE_A_(0, 0, 0);
    STAGE_B_(0, 0, 0);
    STAGE_B_(0, 1, 0);
    STAGE_A_(0, 1, 0);
    STAGE_A_(1, 0, 1);
    STAGE_B_(1, 0, 1);
    STAGE_B_(1, 1, 1);
    asm volatile("s_waitcnt vmcnt(6)" ::: "memory");
    BARRIER_;

    #pragma unroll 1
    for (int t = 0; t < NT - 2; t += 2) {
        TILEFULL(t, 0);
        TILEFULL(t + 1, 1);
    }
    TILEEPI(NT - 2, 0);
    TILELAST(1);

#undef STAGE_A_
#undef STAGE_B_
#undef LOAD_A_
#undef LOAD_B_
#undef MMA_
#undef BARRIER_
#undef WAITL0_
#undef TILEFULL
#undef TILEEPI
#undef TILELAST

    // ---- epilogue: acc[mh*4+mt][nh*2+nt] -> C
    if constexpr (OUT_BF16) {
        bf16_t* C = (bf16_t*)Cv;
        #pragma unroll
        for (int mt = 0; mt < 8; ++mt)
            #pragma unroll
            for (int rg = 0; rg < 4; ++rg) {
                int row = m0 + wm * 128 + (mt >> 2) * 64 + (mt & 3) * 16 + quad * 4 + rg;
                #pragma unroll
                for (int nt = 0; nt < 4; ++nt) {
                    int col = n0 + wn * 64 + nt * 16 + l16;
                    C[(size_t)row * N + col] = __float2bfloat16(acc[mt][nt][rg]);
                }
            }
    } else {
        float* C = (float*)Cv;
        float bv[4];
        #pragma unroll
        for (int nt = 0; nt < 4; ++nt)
            bv[nt] = ADD_BIAS ? bias[n0 + wn * 64 + nt * 16 + l16] : 0.f;
        #pragma unroll
        for (int mt = 0; mt < 8; ++mt)
            #pragma unroll
            for (int rg = 0; rg < 4; ++rg) {
                int row = m0 + wm * 128 + (mt >> 2) * 64 + (mt & 3) * 16 + quad * 4 + rg;
                #pragma unroll
                for (int nt = 0; nt < 4; ++nt) {
                    int col = n0 + wn * 64 + nt * 16 + l16;
                    C[(size_t)row * N + col] = acc[mt][nt][rg] + bv[nt];
                }
            }
    }
}

// ---------------- fused attention for one (b, h, 128-query tile) ----------------
__global__ __launch_bounds__(256, 2) void k_attn(
    const bf16_t* __restrict__ Q, const bf16_t* __restrict__ Kc,
    const bf16_t* __restrict__ Vc, const float* __restrict__ vip,
    bf16_t* __restrict__ Mrg) {
    __shared__ __align__(16) bf16_t Qs[128 * 64];
    __shared__ __align__(16) bf16_t Ks[96 * 64];
    __shared__ __align__(16) bf16_t Vt[64 * 96];
    __shared__ __align__(16) bf16_t Ps[128 * 96];
    const int tid = threadIdx.x;
    const int qb = blockIdx.x, h = blockIdx.y, b = blockIdx.z;
    const int wave = tid >> 6, lane = tid & 63;
    const int quad = lane >> 4, l16 = lane & 15;

    const bf16_t* Qg = Q + ((size_t)(b * 4096 + qb * 128)) * 1280 + h * 64;
    #pragma unroll
    for (int j = 0; j < 4; ++j) {
        int c = tid + j * 256;
        int r = c >> 3, o = (c & 7) * 8;
        gld_lds16(Qg + (size_t)r * 1280 + o, Qs + c * 8);
    }
    bf16_t z = __float2bfloat16(0.f);
    for (int i = 77 * 64 + tid; i < 96 * 64; i += 256) Ks[i] = z;
    for (int i = tid; i < 64 * 19; i += 256) {
        int d = i / 19, kk = 77 + i % 19;
        Vt[d * 96 + kk] = z;
    }
    for (int c = tid; c < 616; c += 256) {
        int r = c >> 3, o = (c & 7) * 8;
        size_t gi = ((size_t)(b * 77 + r)) * 1280 + h * 64 + o;
        int4 kv = *(const int4*)(Kc + gi);
        *(int4*)(Ks + r * 64 + o) = kv;
        int4 vv = *(const int4*)(Vc + gi);
        const bf16_t* ve = (const bf16_t*)&vv;
        #pragma unroll
        for (int j = 0; j < 8; ++j) Vt[(o + j) * 96 + r] = ve[j];
    }
    __syncthreads();

    f32x4 sacc[2][6] = {};
    #pragma unroll
    for (int ks = 0; ks < 2; ++ks) {
        bf16x8 aq[2], bk[6];
        #pragma unroll
        for (int mt = 0; mt < 2; ++mt)
            aq[mt] = *(const bf16x8*)(Qs + (wave * 32 + mt * 16 + l16) * 64 + ks * 32 + quad * 8);
        #pragma unroll
        for (int nt = 0; nt < 6; ++nt)
            bk[nt] = *(const bf16x8*)(Ks + (nt * 16 + l16) * 64 + ks * 32 + quad * 8);
        #pragma unroll
        for (int mt = 0; mt < 2; ++mt)
            #pragma unroll
            for (int nt = 0; nt < 6; ++nt)
                sacc[mt][nt] = __builtin_amdgcn_mfma_f32_16x16x32_bf16(aq[mt], bk[nt], sacc[mt][nt], 0, 0, 0);
    }
    #pragma unroll
    for (int mt = 0; mt < 2; ++mt)
        #pragma unroll
        for (int nt = 0; nt < 6; ++nt)
            #pragma unroll
            for (int rg = 0; rg < 4; ++rg) {
                int row = wave * 32 + mt * 16 + quad * 4 + rg;
                int col = nt * 16 + l16;
                Ps[row * 96 + col] = __float2bfloat16(sacc[mt][nt][rg] * 0.125f);
            }
    __syncthreads();

    {
        int row = tid >> 1, half = tid & 1;
        int cbeg = half ? 39 : 0, cend = half ? 77 : 39;
        bf16_t* prow = Ps + row * 96;
        float mx = -1e30f;
        for (int c = cbeg; c < cend; ++c) mx = fmaxf(mx, __bfloat162float(prow[c]));
        mx = fmaxf(mx, __shfl_xor(mx, 1));
        float sm = 0.f;
        for (int c = cbeg; c < cend; ++c) sm += __expf(__bfloat162float(prow[c]) - mx);
        sm += __shfl_xor(sm, 1);
        float inv = 1.f / sm;
        for (int c = cbeg; c < cend; ++c)
            prow[c] = __float2bfloat16(__expf(__bfloat162float(prow[c]) - mx) * inv);
    }
    __syncthreads();

    f32x4 oacc[2][4] = {};
    #pragma unroll
    for (int ks = 0; ks < 3; ++ks) {
        bf16x8 ap[2], bv[4];
        #pragma unroll
        for (int mt = 0; mt < 2; ++mt)
            ap[mt] = *(const bf16x8*)(Ps + (wave * 32 + mt * 16 + l16) * 96 + ks * 32 + quad * 8);
        #pragma unroll
        for (int nt = 0; nt < 4; ++nt)
            bv[nt] = *(const bf16x8*)(Vt + (nt * 16 + l16) * 96 + ks * 32 + quad * 8);
        #pragma unroll
        for (int mt = 0; mt < 2; ++mt)
            #pragma unroll
            for (int nt = 0; nt < 4; ++nt)
                oacc[mt][nt] = __builtin_amdgcn_mfma_f32_16x16x32_bf16(ap[mt], bv[nt], oacc[mt][nt], 0, 0, 0);
    }
    #pragma unroll
    for (int nt = 0; nt < 4; ++nt) {
        int col = nt * 16 + l16;
        float add = vip[b * 1280 + h * 64 + col];
        #pragma unroll
        for (int mt = 0; mt < 2; ++mt)
            #pragma unroll
            for (int rg = 0; rg < 4; ++rg) {
                int row = wave * 32 + mt * 16 + quad * 4 + rg;
                Mrg[((size_t)(b * 4096 + qb * 128 + row)) * 1280 + h * 64 + col] =
                    __float2bfloat16(oacc[mt][nt][rg] + add);
            }
    }
}

extern "C" void kernel_launch(void* const* d_in, const int* in_sizes, int n_in,
                              void* d_out, int out_size, void* d_ws, size_t ws_size,
                              hipStream_t stream) {
    (void)in_sizes; (void)n_in; (void)out_size; (void)ws_size;
    const float* hs  = (const float*)d_in[0];
    const float* enc = (const float*)d_in[1];
    const float* ae  = (const float*)d_in[2];
    const float* Wq  = (const float*)d_in[3];
    const float* Wk  = (const float*)d_in[4];
    const float* Wv  = (const float*)d_in[5];
    const float* Wva = (const float*)d_in[7];
    const float* Wo  = (const float*)d_in[8];
    const float* bo  = (const float*)d_in[9];
    float* out = (float*)d_out;

    char* ws = (char*)d_ws;
    size_t off = 0;
    auto alloc = [&](size_t bytes) -> void* {
        void* p = ws + off;
        off += (bytes + 255) & ~(size_t)255;
        return p;
    };
    bf16_t* Xb  = (bf16_t*)alloc((size_t)32768 * 1280 * 2);
    bf16_t* Qb  = (bf16_t*)alloc((size_t)32768 * 1280 * 2);
    bf16_t* Mrg = (bf16_t*)alloc((size_t)32768 * 1280 * 2);
    bf16_t* Eb  = (bf16_t*)alloc((size_t)640 * 2048 * 2);
    bf16_t* WqT = (bf16_t*)alloc((size_t)1280 * 1280 * 2);
    bf16_t* WkT = (bf16_t*)alloc((size_t)1280 * 2048 * 2);
    bf16_t* WvT = (bf16_t*)alloc((size_t)1280 * 2048 * 2);
    bf16_t* WoT = (bf16_t*)alloc((size_t)1280 * 1280 * 2);
    bf16_t* Kc  = (bf16_t*)alloc((size_t)640 * 1280 * 2);
    bf16_t* Vc  = (bf16_t*)alloc((size_t)640 * 1280 * 2);
    float*  vip = (float*)alloc((size_t)8 * 1280 * 4);

    k_cast<<<40960, 256, 0, stream>>>(hs, Xb, (long)32768 * 1280);
    k_cast_pad<<<1280, 256, 0, stream>>>(enc, Eb, 616, 640, 2048);
    k_transpose_cast<<<dim3(40, 40), 256, 0, stream>>>(Wq, WqT, 1280, 1280);
    k_transpose_cast<<<dim3(40, 64), 256, 0, stream>>>(Wk, WkT, 2048, 1280);
    k_transpose_cast<<<dim3(40, 64), 256, 0, stream>>>(Wv, WvT, 2048, 1280);
    k_transpose_cast<<<dim3(40, 40), 256, 0, stream>>>(Wo, WoT, 1280, 1280);
    k_adapter<<<40, 256, 0, stream>>>(ae, Wva, vip);

    // big projections: 256^2 8-phase kernel. 128 M-tiles x 5 N-tiles = 640
    // blocks, 640 % 8 == 0 -> XCD swizzle, 16 M-tiles per XCD band, N innermost.
    k_gemm256<true, false><<<640, 512, 0, stream>>>(Xb, WqT, Qb, nullptr, 32768, 1280, 1280, 5, 16);
    // small K/V projections stay on the 128^2 kernel (M=640)
    k_gemm_bt<true, false, false><<<dim3(10, 5), 256, 0, stream>>>(Eb, WkT, Kc, nullptr, 640, 1280, 2048, 0, 0);
    k_gemm_bt<true, false, false><<<dim3(10, 5), 256, 0, stream>>>(Eb, WvT, Vc, nullptr, 640, 1280, 2048, 0, 0);

    k_attn<<<dim3(32, 20, 8), 256, 0, stream>>>(Qb, Kc, Vc, vip, Mrg);

    k_gemm256<false, true><<<640, 512, 0, stream>>>(Mrg, WoT, out, bo, 32768, 1280, 1280, 5, 16);
}

// Round 2
// 830.844 us; speedup vs baseline: 1.0405x; 1.0154x over previous
//
#include <hip/hip_runtime.h>
#include <hip/hip_bf16.h>
#include <cstdint>
#include <cstddef>

typedef __hip_bfloat16 bf16_t;
typedef __attribute__((ext_vector_type(8))) __bf16 bf16x8;
typedef __attribute__((ext_vector_type(4))) float f32x4;

__device__ __forceinline__ void gld_lds16(const void* g, void* l) {
    __builtin_amdgcn_global_load_lds(
        (const __attribute__((address_space(1))) void*)(g),
        (__attribute__((address_space(3))) void*)(l), 16, 0, 0);
}

// ---------------- cast fp32 -> bf16 (n % 4 == 0) ----------------
__global__ void k_cast(const float* __restrict__ in, bf16_t* __restrict__ out, long n) {
    long i = ((long)blockIdx.x * blockDim.x + threadIdx.x) * 4;
    if (i >= n) return;
    float4 v = *(const float4*)(in + i);
    out[i + 0] = __float2bfloat16(v.x);
    out[i + 1] = __float2bfloat16(v.y);
    out[i + 2] = __float2bfloat16(v.z);
    out[i + 3] = __float2bfloat16(v.w);
}

// cast with zero row padding: rows [rows_in, rows_out) -> 0
__global__ void k_cast_pad(const float* __restrict__ in, bf16_t* __restrict__ out,
                           int rows_in, int rows_out, int cols) {
    long i = ((long)blockIdx.x * blockDim.x + threadIdx.x) * 4;
    long n = (long)rows_out * cols;
    if (i >= n) return;
    int r = (int)(i / cols);
    if (r < rows_in) {
        float4 v = *(const float4*)(in + i);
        out[i + 0] = __float2bfloat16(v.x);
        out[i + 1] = __float2bfloat16(v.y);
        out[i + 2] = __float2bfloat16(v.z);
        out[i + 3] = __float2bfloat16(v.w);
    } else {
        bf16_t z = __float2bfloat16(0.f);
        out[i + 0] = z; out[i + 1] = z; out[i + 2] = z; out[i + 3] = z;
    }
}

// ---------------- paired transpose + cast: z selects (in0->out0, in1->out1) ----------------
__global__ void k_transpose_cast2(const float* __restrict__ in0, bf16_t* __restrict__ out0,
                                  const float* __restrict__ in1, bf16_t* __restrict__ out1,
                                  int R, int C) {
    __shared__ float tile[32][33];
    const float* in = blockIdx.z ? in1 : in0;
    bf16_t* out = blockIdx.z ? out1 : out0;
    int bx = blockIdx.x * 32;
    int by = blockIdx.y * 32;
    int tx = threadIdx.x & 31, ty = threadIdx.x >> 5;
    #pragma unroll
    for (int j = 0; j < 32; j += 8)
        tile[ty + j][tx] = in[(size_t)(by + ty + j) * C + bx + tx];
    __syncthreads();
    #pragma unroll
    for (int j = 0; j < 32; j += 8)
        out[(size_t)(bx + ty + j) * R + by + tx] = __float2bfloat16(tile[tx][ty + j]);
}

// ---------------- adapter: v_ip[b][n] = sum_k ae[b][k] * Wva[k][n] ----------------
__global__ void k_adapter(const float* __restrict__ ae, const float* __restrict__ Wva,
                          float* __restrict__ vip) {
    int g = blockIdx.x * 256 + threadIdx.x;
    int b = g / 1280, n = g % 1280;
    const float* a = ae + b * 768;
    float acc = 0.f;
    for (int k = 0; k < 768; ++k) acc += a[k] * Wva[(size_t)k * 1280 + n];
    vip[g] = acc;
}

// ---------------- bf16 GEMM: C[M,N] = A[M,K] @ Bt[N,K]^T (+bias) ----------------
// 128x128 tile, BK=32, 4 waves each 64x64. m97 structure — used for the
// merged K/V projection GEMM (M=640, N=2560, K=2048).
template <bool OUT_BF16, bool ADD_BIAS, bool SWZ>
__global__ __launch_bounds__(256, 2) void k_gemm_bt(
    const bf16_t* __restrict__ A, const bf16_t* __restrict__ Bt,
    void* __restrict__ Cv, const float* __restrict__ bias, int M, int N, int K,
    int snt, int mtx) {
    __shared__ __align__(16) bf16_t As[128 * 32];
    __shared__ __align__(16) bf16_t Bs[128 * 32];
    const int tid = threadIdx.x;
    int m0, n0;
    if constexpr (SWZ) {
        int id = blockIdx.x;
        int xcd = id & 7, j = id >> 3;
        m0 = (xcd * mtx + j / snt) * 128;
        n0 = (j % snt) * 128;
    } else {
        m0 = blockIdx.y * 128;
        n0 = blockIdx.x * 128;
    }
    const int wave = tid >> 6, lane = tid & 63;
    const int wm = (wave >> 1) * 64, wn = (wave & 1) * 64;
    const int quad = lane >> 4, l16 = lane & 15;

    f32x4 acc[4][4] = {};

    const int c0 = tid, c1 = tid + 256;
    const int r0 = c0 >> 2, o0 = (c0 & 3) * 8;
    const int r1 = c1 >> 2, o1 = (c1 & 3) * 8;
    const bf16_t* a0 = A + (size_t)(m0 + r0) * K + o0;
    const bf16_t* a1 = A + (size_t)(m0 + r1) * K + o1;
    const bf16_t* b0 = Bt + (size_t)(n0 + r0) * K + o0;
    const bf16_t* b1 = Bt + (size_t)(n0 + r1) * K + o1;

    for (int k0 = 0; k0 < K; k0 += 32) {
        __syncthreads();
        gld_lds16(a0 + k0, As + c0 * 8);
        gld_lds16(a1 + k0, As + c1 * 8);
        gld_lds16(b0 + k0, Bs + c0 * 8);
        gld_lds16(b1 + k0, Bs + c1 * 8);
        __syncthreads();
        bf16x8 af[4], bfv[4];
        #pragma unroll
        for (int t = 0; t < 4; ++t) {
            af[t]  = *(const bf16x8*)(As + (wm + t * 16 + l16) * 32 + quad * 8);
            bfv[t] = *(const bf16x8*)(Bs + (wn + t * 16 + l16) * 32 + quad * 8);
        }
        #pragma unroll
        for (int mt = 0; mt < 4; ++mt)
            #pragma unroll
            for (int nt = 0; nt < 4; ++nt)
                acc[mt][nt] = __builtin_amdgcn_mfma_f32_16x16x32_bf16(af[mt], bfv[nt], acc[mt][nt], 0, 0, 0);
    }

    if constexpr (OUT_BF16) {
        bf16_t* C = (bf16_t*)Cv;
        #pragma unroll
        for (int mt = 0; mt < 4; ++mt)
            #pragma unroll
            for (int rg = 0; rg < 4; ++rg) {
                int row = m0 + wm + mt * 16 + quad * 4 + rg;
                #pragma unroll
                for (int nt = 0; nt < 4; ++nt) {
                    int col = n0 + wn + nt * 16 + l16;
                    C[(size_t)row * N + col] = __float2bfloat16(acc[mt][nt][rg]);
                }
            }
    } else {
        float* C = (float*)Cv;
        float bv[4];
        #pragma unroll
        for (int nt = 0; nt < 4; ++nt)
            bv[nt] = ADD_BIAS ? bias[n0 + wn + nt * 16 + l16] : 0.f;
        #pragma unroll
        for (int mt = 0; mt < 4; ++mt)
            #pragma unroll
            for (int rg = 0; rg < 4; ++rg) {
                int row = m0 + wm + mt * 16 + quad * 4 + rg;
                #pragma unroll
                for (int nt = 0; nt < 4; ++nt) {
                    int col = n0 + wn + nt * 16 + l16;
                    C[(size_t)row * N + col] = acc[mt][nt][rg] + bv[nt];
                }
            }
    }
}

// ---------------- bf16 GEMM, 256x256 tile, BK=64, read-ahead 4-phase pipeline --------
// 512 threads = 8 waves (2M x 4N), per-wave output 128x64. LDS 128 KiB double buffer.
// KEY CHANGE vs round 1: each phase's ds_reads feed the NEXT phase's MFMA
// (counted lgkmcnt 4/8/8/-), so the LDS drain overlaps the current MFMA cluster.
//
// Per tile t (RB = t&1, RN = RB^1), phases:
//  P1: read bf1<=B1(t)[4]; stage A1(t+1)->As[RN];  vm(8);bar; lg(4)  [afA,bf0 done]; MFMA A0B0; bar
//  P2: read afB<=A1(t)[8]; stage A0(t+2)->As[RB];  vm(8);bar; lg(8)  [bf1 done];     MFMA A0B1; bar
//  P3: read afA<=A0(t+1)[8]; stage B0(t+2)->Bs[RB];vm(8);bar; lg(8)  [afB done];     MFMA A1B0; bar
//  P4: read bf0<=B0(t+1)[4]; stage B1(t+2)->Bs[RB];vm(8);bar; (no lg needed);        MFMA A1B1; bar
// Stage-death: region overwritten at phase q had its tile-t readers drained by the
// counted lg of an earlier phase + a barrier (verified per-region). Residency:
// vmcnt(8) at phase p completes the stage issued at p-4 (5-phase lookahead),
// published by the same phase's barrier before the read at p+1.
template <bool OUT_BF16, bool ADD_BIAS, int KC>
__global__ __launch_bounds__(512, 2) void k_gemm256(
    const bf16_t* __restrict__ A, const bf16_t* __restrict__ Bt,
    void* __restrict__ Cv, const float* __restrict__ bias,
    int N, int snt, int mtx) {
    __shared__ __align__(16) bf16_t As[2][256 * 64];
    __shared__ __align__(16) bf16_t Bs[2][256 * 64];
    const int tid = threadIdx.x;
    const int id = blockIdx.x;
    const int xcd = id & 7, jb = id >> 3;
    const int m0 = (xcd * mtx + jb / snt) * 256;
    const int n0 = (jb % snt) * 256;
    const int wave = tid >> 6, lane = tid & 63;
    const int wm = wave >> 2, wn = wave & 3;
    const int quad = lane >> 4, l16 = lane & 15;

    // ---- staging geometry
    const int lr0 = tid >> 3;
    const int cst = ((tid & 7) * 8) ^ ((lr0 & 7) * 8);
    const bf16_t* pA0 = A + (size_t)(m0 + lr0) * KC + cst;
    const bf16_t* pA1 = pA0 + (size_t)128 * KC;
    const bf16_t* pB0 = Bt + (size_t)(n0 + ((lr0 >> 5) << 6) + (lr0 & 31)) * KC + cst;
    const bf16_t* pB1 = pB0 + (size_t)128 * KC;
    const int eA0 = tid * 8, eA1 = 4096 + tid * 8;

    // ---- fragment read geometry
    const int xorc = (l16 & 7) * 8;
    const int c0x = (quad * 8) ^ xorc;
    const int c1x = (32 + quad * 8) ^ xorc;
    const int arow = (wm * 64 + l16) * 64;
    const int brow = (wn * 32 + l16) * 64;

    f32x4 acc[8][4] = {};
    bf16x8 afA[4][2], afB[4][2], bf0[2][2], bf1[2][2];

#define SA0_(WB, T) do { size_t ko_ = (size_t)(T) * 64; \
    gld_lds16(pA0 + ko_, &As[WB][eA0]); gld_lds16(pA1 + ko_, &As[WB][eA1]); } while (0)
#define SA1_(WB, T) do { size_t ko_ = (size_t)(T) * 64 + (size_t)64 * KC; \
    gld_lds16(pA0 + ko_, &As[WB][8192 + eA0]); gld_lds16(pA1 + ko_, &As[WB][8192 + eA1]); } while (0)
#define SB0_(WB, T) do { size_t ko_ = (size_t)(T) * 64; \
    gld_lds16(pB0 + ko_, &Bs[WB][eA0]); gld_lds16(pB1 + ko_, &Bs[WB][eA1]); } while (0)
#define SB1_(WB, T) do { size_t ko_ = (size_t)(T) * 64 + (size_t)32 * KC; \
    gld_lds16(pB0 + ko_, &Bs[WB][8192 + eA0]); gld_lds16(pB1 + ko_, &Bs[WB][8192 + eA1]); } while (0)
#define RD_AFA(RB_) do { _Pragma("unroll") for (int mt = 0; mt < 4; ++mt) { \
    const bf16_t* p_ = &As[RB_][arow + mt * 1024]; \
    afA[mt][0] = *(const bf16x8*)(p_ + c0x); afA[mt][1] = *(const bf16x8*)(p_ + c1x); } } while (0)
#define RD_AFB(RB_) do { _Pragma("unroll") for (int mt = 0; mt < 4; ++mt) { \
    const bf16_t* p_ = &As[RB_][8192 + arow + mt * 1024]; \
    afB[mt][0] = *(const bf16x8*)(p_ + c0x); afB[mt][1] = *(const bf16x8*)(p_ + c1x); } } while (0)
#define RD_BF0(RB_) do { _Pragma("unroll") for (int nt = 0; nt < 2; ++nt) { \
    const bf16_t* p_ = &Bs[RB_][brow + nt * 1024]; \
    bf0[nt][0] = *(const bf16x8*)(p_ + c0x); bf0[nt][1] = *(const bf16x8*)(p_ + c1x); } } while (0)
#define RD_BF1(RB_) do { _Pragma("unroll") for (int nt = 0; nt < 2; ++nt) { \
    const bf16_t* p_ = &Bs[RB_][8192 + brow + nt * 1024]; \
    bf1[nt][0] = *(const bf16x8*)(p_ + c0x); bf1[nt][1] = *(const bf16x8*)(p_ + c1x); } } while (0)
#define MMA_(AF, BF, MB, NB) do { _Pragma("unroll") \
    for (int mt = 0; mt < 4; ++mt) _Pragma("unroll") \
    for (int nt = 0; nt < 2; ++nt) _Pragma("unroll") \
    for (int ks = 0; ks < 2; ++ks) \
      acc[(MB) + mt][(NB) + nt] = __builtin_amdgcn_mfma_f32_16x16x32_bf16( \
          AF[mt][ks], BF[nt][ks], acc[(MB) + mt][(NB) + nt], 0, 0, 0); } while (0)
#define BAR_ asm volatile("s_barrier" ::: "memory")
#define VM_(n) asm volatile("s_waitcnt vmcnt(" #n ")" ::: "memory")
#define LG_(n) do { asm volatile("s_waitcnt lgkmcnt(" #n ")" ::: "memory"); \
    __builtin_amdgcn_sched_barrier(0); } while (0)
#define P1_ __builtin_amdgcn_s_setprio(1)
#define P0_ __builtin_amdgcn_s_setprio(0)

#define TILE_(T, RB) do { \
    RD_BF1(RB); SA1_((RB) ^ 1, (T) + 1); VM_(8); BAR_; \
    LG_(4); P1_; MMA_(afA, bf0, 0, 0); P0_; BAR_; \
    RD_AFB(RB); SA0_(RB, (T) + 2); VM_(8); BAR_; \
    LG_(8); P1_; MMA_(afA, bf1, 0, 2); P0_; BAR_; \
    RD_AFA((RB) ^ 1); SB0_(RB, (T) + 2); VM_(8); BAR_; \
    LG_(8); P1_; MMA_(afB, bf0, 4, 0); P0_; BAR_; \
    RD_BF0((RB) ^ 1); SB1_(RB, (T) + 2); VM_(8); BAR_; \
    P1_; MMA_(afB, bf1, 4, 2); P0_; BAR_; \
  } while (0)

    const int NT = KC >> 6;  // even, >= 4

    // prologue: tile0 all 4 regions + tile1 A0,B0,B1 (7 half-tiles, in-order)
    SA0_(0, 0); SB0_(0, 0); SB1_(0, 0); SA1_(0, 0);
    SA0_(1, 1); SB0_(1, 1); SB1_(1, 1);
    VM_(8);          // A0(0), B0(0), B1(0) resident
    BAR_;
    RD_AFA(0); RD_BF0(0);

    #pragma unroll 1
    for (int t = 0; t < NT - 2; t += 2) {
        TILE_(t, 0);
        TILE_(t + 1, 1);
    }

    // ---- tail tile NT-2 (buffer 0): only A1(NT-1) still staged
    RD_BF1(0); SA1_(1, NT - 1); VM_(8); BAR_;
    LG_(4); P1_; MMA_(afA, bf0, 0, 0); P0_; BAR_;
    RD_AFB(0); VM_(6); BAR_;
    LG_(8); P1_; MMA_(afA, bf1, 0, 2); P0_; BAR_;
    RD_AFA(1); VM_(4); BAR_;
    LG_(8); P1_; MMA_(afB, bf0, 4, 0); P0_; BAR_;
    RD_BF0(1); VM_(2); BAR_;
    P1_; MMA_(afB, bf1, 4, 2); P0_; BAR_;
    // ---- tail tile NT-1 (buffer 1): no staging, no next-tile reads
    RD_BF1(1); VM_(0); BAR_;
    RD_AFB(1);
    LG_(12); P1_; MMA_(afA, bf0, 0, 0); P0_;
    LG_(8);  P1_; MMA_(afA, bf1, 0, 2); P0_;
    LG_(0);  P1_; MMA_(afB, bf0, 4, 0); P0_;
    P1_; MMA_(afB, bf1, 4, 2); P0_;

#undef SA0_
#undef SA1_
#undef SB0_
#undef SB1_
#undef RD_AFA
#undef RD_AFB
#undef RD_BF0
#undef RD_BF1
#undef MMA_
#undef BAR_
#undef VM_
#undef LG_
#undef P1_
#undef P0_
#undef TILE_

    if constexpr (OUT_BF16) {
        // stage C through LDS (As rows 0-127, Bs rows 128-255) for coalesced
        // 16B stores — direct 2B-scattered stores measured 2x write traffic.
        bf16_t* C = (bf16_t*)Cv;
        __syncthreads();
        bf16_t* eb = wm ? (bf16_t*)Bs : (bf16_t*)As;
        #pragma unroll
        for (int mt = 0; mt < 8; ++mt)
            #pragma unroll
            for (int rg = 0; rg < 4; ++rg) {
                int rr = (mt >> 2) * 64 + (mt & 3) * 16 + quad * 4 + rg;
                #pragma unroll
                for (int nt = 0; nt < 4; ++nt)
                    eb[rr * 256 + wn * 64 + nt * 16 + l16] = __float2bfloat16(acc[mt][nt][rg]);
            }
        __syncthreads();
        #pragma unroll
        for (int pass = 0; pass < 16; ++pass) {
            const bf16_t* sb = (pass < 8) ? (const bf16_t*)As : (const bf16_t*)Bs;
            int r = pass * 16 + (tid >> 5);
            int cc = (tid & 31) * 8;
            *(int4*)(&C[(size_t)(m0 + r) * N + n0 + cc]) =
                *(const int4*)(sb + (r & 127) * 256 + cc);
        }
    } else {
        float* C = (float*)Cv;
        float bv[4];
        #pragma unroll
        for (int nt = 0; nt < 4; ++nt)
            bv[nt] = ADD_BIAS ? bias[n0 + wn * 64 + nt * 16 + l16] : 0.f;
        #pragma unroll
        for (int mt = 0; mt < 8; ++mt)
            #pragma unroll
            for (int rg = 0; rg < 4; ++rg) {
                int row = m0 + wm * 128 + (mt >> 2) * 64 + (mt & 3) * 16 + quad * 4 + rg;
                #pragma unroll
                for (int nt = 0; nt < 4; ++nt) {
                    int col = n0 + wn * 64 + nt * 16 + l16;
                    C[(size_t)row * N + col] = acc[mt][nt][rg] + bv[nt];
                }
            }
    }
}

// ---------------- fused attention for one (b, h, 128-query tile) ----------------
// KV is the merged K/V projection output: [640 rows, 2560], K cols 0-1279, V cols 1280-2559.
__global__ __launch_bounds__(256, 2) void k_attn(
    const bf16_t* __restrict__ Q, const bf16_t* __restrict__ KV,
    const float* __restrict__ vip, bf16_t* __restrict__ Mrg) {
    __shared__ __align__(16) bf16_t Qs[128 * 64];
    __shared__ __align__(16) bf16_t Ks[96 * 64];
    __shared__ __align__(16) bf16_t Vt[64 * 96];
    __shared__ __align__(16) bf16_t Ps[128 * 96];
    const int tid = threadIdx.x;
    const int qb = blockIdx.x, h = blockIdx.y, b = blockIdx.z;
    const int wave = tid >> 6, lane = tid & 63;
    const int quad = lane >> 4, l16 = lane & 15;

    const bf16_t* Qg = Q + ((size_t)(b * 4096 + qb * 128)) * 1280 + h * 64;
    #pragma unroll
    for (int j = 0; j < 4; ++j) {
        int c = tid + j * 256;
        int r = c >> 3, o = (c & 7) * 8;
        gld_lds16(Qg + (size_t)r * 1280 + o, Qs + c * 8);
    }
    bf16_t z = __float2bfloat16(0.f);
    for (int i = 77 * 64 + tid; i < 96 * 64; i += 256) Ks[i] = z;
    for (int i = tid; i < 64 * 19; i += 256) {
        int d = i / 19, kk = 77 + i % 19;
        Vt[d * 96 + kk] = z;
    }
    for (int c = tid; c < 616; c += 256) {
        int r = c >> 3, o = (c & 7) * 8;
        size_t gi = ((size_t)(b * 77 + r)) * 2560 + h * 64 + o;
        int4 kv = *(const int4*)(KV + gi);
        *(int4*)(Ks + r * 64 + o) = kv;
        int4 vv = *(const int4*)(KV + gi + 1280);
        const bf16_t* ve = (const bf16_t*)&vv;
        #pragma unroll
        for (int j = 0; j < 8; ++j) Vt[(o + j) * 96 + r] = ve[j];
    }
    __syncthreads();

    f32x4 sacc[2][6] = {};
    #pragma unroll
    for (int ks = 0; ks < 2; ++ks) {
        bf16x8 aq[2], bk[6];
        #pragma unroll
        for (int mt = 0; mt < 2; ++mt)
            aq[mt] = *(const bf16x8*)(Qs + (wave * 32 + mt * 16 + l16) * 64 + ks * 32 + quad * 8);
        #pragma unroll
        for (int nt = 0; nt < 6; ++nt)
            bk[nt] = *(const bf16x8*)(Ks + (nt * 16 + l16) * 64 + ks * 32 + quad * 8);
        #pragma unroll
        for (int mt = 0; mt < 2; ++mt)
            #pragma unroll
            for (int nt = 0; nt < 6; ++nt)
                sacc[mt][nt] = __builtin_amdgcn_mfma_f32_16x16x32_bf16(aq[mt], bk[nt], sacc[mt][nt], 0, 0, 0);
    }
    #pragma unroll
    for (int mt = 0; mt < 2; ++mt)
        #pragma unroll
        for (int nt = 0; nt < 6; ++nt)
            #pragma unroll
            for (int rg = 0; rg < 4; ++rg) {
                int row = wave * 32 + mt * 16 + quad * 4 + rg;
                int col = nt * 16 + l16;
                Ps[row * 96 + col] = __float2bfloat16(sacc[mt][nt][rg] * 0.125f);
            }
    __syncthreads();

    {
        int row = tid >> 1, half = tid & 1;
        int cbeg = half ? 39 : 0, cend = half ? 77 : 39;
        bf16_t* prow = Ps + row * 96;
        float mx = -1e30f;
        for (int c = cbeg; c < cend; ++c) mx = fmaxf(mx, __bfloat162float(prow[c]));
        mx = fmaxf(mx, __shfl_xor(mx, 1));
        float sm = 0.f;
        for (int c = cbeg; c < cend; ++c) sm += __expf(__bfloat162float(prow[c]) - mx);
        sm += __shfl_xor(sm, 1);
        float inv = 1.f / sm;
        for (int c = cbeg; c < cend; ++c)
            prow[c] = __float2bfloat16(__expf(__bfloat162float(prow[c]) - mx) * inv);
    }
    __syncthreads();

    f32x4 oacc[2][4] = {};
    #pragma unroll
    for (int ks = 0; ks < 3; ++ks) {
        bf16x8 ap[2], bv[4];
        #pragma unroll
        for (int mt = 0; mt < 2; ++mt)
            ap[mt] = *(const bf16x8*)(Ps + (wave * 32 + mt * 16 + l16) * 96 + ks * 32 + quad * 8);
        #pragma unroll
        for (int nt = 0; nt < 4; ++nt)
            bv[nt] = *(const bf16x8*)(Vt + (nt * 16 + l16) * 96 + ks * 32 + quad * 8);
        #pragma unroll
        for (int mt = 0; mt < 2; ++mt)
            #pragma unroll
            for (int nt = 0; nt < 4; ++nt)
                oacc[mt][nt] = __builtin_amdgcn_mfma_f32_16x16x32_bf16(ap[mt], bv[nt], oacc[mt][nt], 0, 0, 0);
    }
    // stage output in LDS (reuse Ps as [128][64]) -> coalesced 16B stores
    __syncthreads();
    #pragma unroll
    for (int nt = 0; nt < 4; ++nt) {
        int col = nt * 16 + l16;
        float add = vip[b * 1280 + h * 64 + col];
        #pragma unroll
        for (int mt = 0; mt < 2; ++mt)
            #pragma unroll
            for (int rg = 0; rg < 4; ++rg) {
                int row = wave * 32 + mt * 16 + quad * 4 + rg;
                Ps[row * 64 + col] = __float2bfloat16(oacc[mt][nt][rg] + add);
            }
    }
    __syncthreads();
    #pragma unroll
    for (int pass = 0; pass < 4; ++pass) {
        int r = pass * 32 + (tid >> 3);
        int cc = (tid & 7) * 8;
        *(int4*)(Mrg + ((size_t)(b * 4096 + qb * 128 + r)) * 1280 + h * 64 + cc) =
            *(const int4*)(Ps + r * 64 + cc);
    }
}

extern "C" void kernel_launch(void* const* d_in, const int* in_sizes, int n_in,
                              void* d_out, int out_size, void* d_ws, size_t ws_size,
                              hipStream_t stream) {
    (void)in_sizes; (void)n_in; (void)out_size; (void)ws_size;
    const float* hs  = (const float*)d_in[0];
    const float* enc = (const float*)d_in[1];
    const float* ae  = (const float*)d_in[2];
    const float* Wq  = (const float*)d_in[3];
    const float* Wk  = (const float*)d_in[4];
    const float* Wv  = (const float*)d_in[5];
    const float* Wva = (const float*)d_in[7];
    const float* Wo  = (const float*)d_in[8];
    const float* bo  = (const float*)d_in[9];
    float* out = (float*)d_out;

    char* ws = (char*)d_ws;
    size_t off = 0;
    auto alloc = [&](size_t bytes) -> void* {
        void* p = ws + off;
        off += (bytes + 255) & ~(size_t)255;
        return p;
    };
    bf16_t* Xb   = (bf16_t*)alloc((size_t)32768 * 1280 * 2);
    bf16_t* Qb   = (bf16_t*)alloc((size_t)32768 * 1280 * 2);
    bf16_t* Mrg  = (bf16_t*)alloc((size_t)32768 * 1280 * 2);
    bf16_t* Eb   = (bf16_t*)alloc((size_t)640 * 2048 * 2);
    bf16_t* WqT  = (bf16_t*)alloc((size_t)1280 * 1280 * 2);
    bf16_t* WkvT = (bf16_t*)alloc((size_t)2560 * 2048 * 2);
    bf16_t* WoT  = (bf16_t*)alloc((size_t)1280 * 1280 * 2);
    bf16_t* KVc  = (bf16_t*)alloc((size_t)640 * 2560 * 2);
    float*  vip  = (float*)alloc((size_t)8 * 1280 * 4);

    k_cast<<<40960, 256, 0, stream>>>(hs, Xb, (long)32768 * 1280);
    k_cast_pad<<<1280, 256, 0, stream>>>(enc, Eb, 616, 640, 2048);
    k_transpose_cast2<<<dim3(40, 40, 2), 256, 0, stream>>>(Wq, WqT, Wo, WoT, 1280, 1280);
    k_transpose_cast2<<<dim3(40, 64, 2), 256, 0, stream>>>(Wk, WkvT, Wv, WkvT + (size_t)1280 * 2048, 2048, 1280);
    k_adapter<<<40, 256, 0, stream>>>(ae, Wva, vip);

    // big projections: 256^2 read-ahead pipeline. 128 M-tiles x 5 N-tiles = 640
    // blocks, XCD swizzle (16 M-tiles per XCD band, N innermost).
    k_gemm256<true, false, 1280><<<640, 512, 0, stream>>>(Xb, WqT, Qb, nullptr, 1280, 5, 16);
    // merged K+V projection: [640,2048] @ [2560,2048]^T -> [640,2560]
    k_gemm_bt<true, false, false><<<dim3(20, 5), 256, 0, stream>>>(Eb, WkvT, KVc, nullptr, 640, 2560, 2048, 0, 0);

    k_attn<<<dim3(32, 20, 8), 256, 0, stream>>>(Qb, KVc, vip, Mrg);

    k_gemm256<false, true, 1280><<<640, 512, 0, stream>>>(Mrg, WoT, out, bo, 1280, 5, 16);
}